// Round 10
// baseline (60.805 us; speedup 1.0000x reference)
//
#include <hip/hip_runtime.h>

#define NN 5000
#define TT 12
#define DAYD 8
#define FF 7
#define DIMD 96
#define SEGCAP 80
#define NB 1024   // persistent blocks: 4/CU at launch_bounds(256,4)

typedef unsigned int uint32;
typedef unsigned long long ull;
typedef uint32 uvec4 __attribute__((ext_vector_type(4)));

// ---------------------------------------------------------------------------
// Kernel 1: persistent software-pipelined scan+gather.
//   AGG[n][t*8+d] = mean over nnz(adj[n]) of data[t][j][d]
// adj entries are exactly 1.0/0.0 -> deg == count; masks[1] == 0 because
// jnp.power is ELEMENTWISE and adj is binary (the L=2 mask vanishes).
// Round-10 theory: per-block READ DUTY CYCLE is the limiter (loads only
// outstanding ~35% of block lifetime). Fix: grid-stride persistent blocks
// that PREFETCH row r+NB's 5 chunks before ballot+gather of row r — loads
// stay in flight across the compute phases (counted vmcnt, not drain).
// ---------------------------------------------------------------------------
__global__ void __launch_bounds__(256, 4)
agg_kernel(const uint32* __restrict__ adj,
           const float* __restrict__ data,
           float* __restrict__ agg_out) {
    __shared__ unsigned short s_cols[4][SEGCAP];
    __shared__ int s_wcnt[4];

    const int tid = threadIdx.x;
    const int wave = tid >> 6, lane = tid & 63;
    const ull lmask = (1ull << lane) - 1ull;
    const int cbase = wave * 64 + lane;   // chunk index for i=0 (step 256)

    uvec4 vC[5], vN[5];

    // prologue: load first row
    {
        const uvec4* row = (const uvec4*)(adj + (size_t)blockIdx.x * NN);
        #pragma unroll
        for (int i = 0; i < 5; ++i) {
            const int c = cbase + i * 256;
            vC[i] = (c < 1250) ? __builtin_nontemporal_load(&row[c])
                               : (uvec4)(0u, 0u, 0u, 0u);
        }
    }

    for (int r = blockIdx.x; r < NN; r += NB) {
        // 1) issue next row's loads FIRST (in flight across ballot+gather)
        const int rn = r + NB;
        if (rn < NN) {
            const uvec4* row = (const uvec4*)(adj + (size_t)rn * NN);
            #pragma unroll
            for (int i = 0; i < 5; ++i) {
                const int c = cbase + i * 256;
                vN[i] = (c < 1250) ? __builtin_nontemporal_load(&row[c])
                                   : (uvec4)(0u, 0u, 0u, 0u);
            }
        }

        // 2) ballot-compact current row into wave-private LDS segments
        int cnt = 0;
        #pragma unroll
        for (int i = 0; i < 5; ++i) {
            #pragma unroll
            for (int q = 0; q < 4; ++q) {
                const bool nz = vC[i][q] != 0u;
                const ull m = __ballot(nz);
                if (nz) {
                    const int pos = cnt + (int)__popcll(m & lmask);
                    if (pos < SEGCAP)
                        s_cols[wave][pos] = (unsigned short)((cbase + i * 256) * 4 + q);
                }
                cnt += (int)__popcll(m);
            }
        }
        if (lane == 0) s_wcnt[wave] = (cnt < SEGCAP) ? cnt : SEGCAP;
        __syncthreads();

        // 3) gather (96 threads; data is L2-resident, loads independent)
        if (tid < DIMD) {
            const int t = tid >> 3, d = tid & 7;
            const float* db = data + (size_t)t * NN * DAYD + d;
            float acc = 0.f;
            int tot = 0;
            #pragma unroll
            for (int w2 = 0; w2 < 4; ++w2) {
                const int c = s_wcnt[w2];
                tot += c;
                const unsigned short* sc = s_cols[w2];
                int e = 0;
                for (; e + 4 <= c; e += 4) {
                    int j0 = sc[e], j1 = sc[e + 1], j2 = sc[e + 2], j3 = sc[e + 3];
                    acc += db[(size_t)j0 * 8] + db[(size_t)j1 * 8]
                         + db[(size_t)j2 * 8] + db[(size_t)j3 * 8];
                }
                for (; e < c; ++e) acc += db[(size_t)sc[e] * 8];
            }
            const float sc2 = (tot > 0) ? (1.f / (float)tot) : 0.f;
            agg_out[(size_t)r * DIMD + tid] = acc * sc2;
        }
        __syncthreads();   // s_cols reusable

        // 4) rotate double buffer
        #pragma unroll
        for (int i = 0; i < 5; ++i) vC[i] = vN[i];
    }
}

// ---------------------------------------------------------------------------
// Kernel 2: sequential T-loop, 8 LANES PER NODE (lane o<7 owns h[o] and
// run_his[o]; lane 7 owns the cur chain). ~12 regs of state -> no scratch.
// Cross-lane h / his_prev via width-8 shuffles. Weights zero-padded to 8
// rows in LDS for branch-free per-lane b128 reads.
// ---------------------------------------------------------------------------
__global__ void __launch_bounds__(256)
seq_kernel(const float* __restrict__ data,
           const float* __restrict__ pos,
           const float* __restrict__ hisW,   // (T, F, 28)
           const float* __restrict__ curW,   // (T, 1, 4)
           const float* __restrict__ hisw,   // (F, 95)
           const float* __restrict__ curw,   // (1, 12)
           const float* __restrict__ agg,    // (N, 96)
           float* __restrict__ fin_out) {    // (N, 96)
    __shared__ float s_W1[TT][8][24];
    __shared__ float s_W2[TT][8][8];
    __shared__ float s_CW[TT][4];

    const int tid = threadIdx.x;
    for (int i = tid; i < TT * 8 * 24; i += 256) {
        int t = i / (8 * 24), r = i - t * 8 * 24;
        int o = r / 24, k = r - o * 24;
        float v = 0.f;
        if (o < FF) {
            if (k < 14)      v = hisW[t * FF * 28 + o * 28 + k];
            else if (k < 21) v = hisW[t * FF * 28 + o * 28 + 21 + (k - 14)];
        }
        s_W1[t][o][k] = v;
    }
    for (int i = tid; i < TT * 8 * 8; i += 256) {
        int t = i / 64, r = i - t * 64;
        int o = r / 8, k = r - o * 8;
        s_W2[t][o][k] = (o < FF && k < FF) ? hisw[o * 95 + t * FF + k] : 0.f;
    }
    if (tid < TT * 4) {
        int t = tid >> 2, q = tid & 3;
        float v;
        if (q == 0)      v = curW[t * 4 + 0];
        else if (q == 1) v = curW[t * 4 + 1];
        else if (q == 2) v = curW[t * 4 + 3];
        else             v = curw[t];
        s_CW[t][q] = v;
    }
    __syncthreads();

    const int g = tid >> 3;
    const int o = tid & 7;
    const int n = blockIdx.x * 32 + g;
    if (n >= NN) return;

    float hp = 0.f;
    float run_his = 0.f;
    float run_cur = 0.f, cur_prev = 0.f;

    #pragma unroll
    for (int t = 0; t < TT; ++t) {
        const size_t dofs = ((size_t)t * NN + n) * DAYD;
        float4 d0 = *(const float4*)(data + dofs);
        float4 d1 = *(const float4*)(data + dofs + 4);
        float4 a0 = *(const float4*)(agg + (size_t)n * DIMD + t * 8);
        float4 a1 = *(const float4*)(agg + (size_t)n * DIMD + t * 8 + 4);
        const float pv = pos[dofs + o];

        float hp0 = __shfl(hp, 0, 8), hp1 = __shfl(hp, 1, 8);
        float hp2 = __shfl(hp, 2, 8), hp3 = __shfl(hp, 3, 8);
        float hp4 = __shfl(hp, 4, 8), hp5 = __shfl(hp, 5, 8);
        float hp6 = __shfl(hp, 6, 8);

        const float4* wo = (const float4*)&s_W1[t][o][0];
        float4 w0 = wo[0], w1 = wo[1], w2 = wo[2];
        float4 w3 = wo[3], w4 = wo[4], w5 = wo[5];
        float s = d0.x * w0.x + d0.y * w0.y + d0.z * w0.z + d0.w * w0.w
                + d1.x * w1.x + d1.y * w1.y + d1.z * w1.z
                + a0.x * w1.w + a0.y * w2.x + a0.z * w2.y + a0.w * w2.z
                + a1.x * w2.w + a1.y * w3.x + a1.z * w3.y
                + hp0 * w3.z + hp1 * w3.w + hp2 * w4.x + hp3 * w4.y
                + hp4 * w4.z + hp5 * w4.w + hp6 * w5.x;
        const float h = fmaxf(s, 0.f) + pv;

        float h0 = __shfl(h, 0, 8), h1 = __shfl(h, 1, 8);
        float h2 = __shfl(h, 2, 8), h3 = __shfl(h, 3, 8);
        float h4 = __shfl(h, 4, 8), h5 = __shfl(h, 5, 8);
        float h6 = __shfl(h, 6, 8);

        const float4* uo = (const float4*)&s_W2[t][o][0];
        float4 u0 = uo[0], u1 = uo[1];
        run_his += h0 * u0.x + h1 * u0.y + h2 * u0.z + h3 * u0.w
                 + h4 * u1.x + h5 * u1.y + h6 * u1.z;
        hp = fmaxf(run_his, 0.f);

        if (o < FF) {
            fin_out[(size_t)n * DIMD + t * FF + o] = h;
        } else {
            float4 cw = *(const float4*)&s_CW[t][0];
            float c = d1.w * cw.x + a1.w * cw.y + cur_prev * cw.z;
            c = fmaxf(c, 0.f) + pv;
            fin_out[(size_t)n * DIMD + 84 + t] = c;
            run_cur += c * cw.w;
            cur_prev = fmaxf(run_cur, 0.f);
        }
    }
}

// ---------------------------------------------------------------------------
// Kernel 3: out = relu(fin @ fw^T). 32-node tiles -> 157 blocks. 4 waves;
// wave w + lane-half own 12 outputs for node = lane&31. fw staged in LDS
// [96][100] (aligned b128 broadcast); fin in LDS pad-97. s_out aliases s_fw.
// ---------------------------------------------------------------------------
__global__ void __launch_bounds__(256)
final_kernel(const float* __restrict__ fin,
             const float* __restrict__ fw,
             float* __restrict__ out) {
    __shared__ float s_fw[96 * 100];   // 38,400 B
    __shared__ float s_fin[32 * 97];   // 12,416 B
    float* s_out = s_fw;               // alias (after barrier)

    const int tid = threadIdx.x;
    const int nbase = blockIdx.x * 32;

    for (int i = tid; i < 96 * 96; i += 256) {
        int o = i / 96, k = i - o * 96;
        s_fw[o * 100 + k] = fw[i];
    }
    for (int i = tid; i < 32 * DIMD; i += 256) {
        int r = i / DIMD, c = i - r * DIMD;
        int nn = nbase + r;
        s_fin[r * 97 + c] = (nn < NN) ? fin[(size_t)nn * DIMD + c] : 0.f;
    }
    __syncthreads();

    const int wave = tid >> 6, lane = tid & 63;
    const int node = lane & 31, dup = lane >> 5;
    const int obase = wave * 24 + dup * 12;

    float acc[12];
    #pragma unroll
    for (int o = 0; o < 12; ++o) acc[o] = 0.f;

    #pragma unroll 2
    for (int k0 = 0; k0 < DIMD; k0 += 4) {
        float f0 = s_fin[node * 97 + k0 + 0];
        float f1 = s_fin[node * 97 + k0 + 1];
        float f2 = s_fin[node * 97 + k0 + 2];
        float f3 = s_fin[node * 97 + k0 + 3];
        #pragma unroll
        for (int o = 0; o < 12; ++o) {
            float4 w = *(const float4*)&s_fw[(obase + o) * 100 + k0];
            acc[o] += f0 * w.x + f1 * w.y + f2 * w.z + f3 * w.w;
        }
    }
    __syncthreads();   // all fw reads done

    #pragma unroll
    for (int o = 0; o < 12; ++o)
        s_out[node * 97 + obase + o] = fmaxf(acc[o], 0.f);
    __syncthreads();

    for (int i = tid; i < 32 * DIMD; i += 256) {
        int r = i / DIMD, c = i - r * DIMD;
        int nn = nbase + r;
        if (nn < NN) out[(size_t)nn * DIMD + c] = s_out[r * 97 + c];
    }
}

extern "C" void kernel_launch(void* const* d_in, const int* in_sizes, int n_in,
                              void* d_out, int out_size, void* d_ws, size_t ws_size,
                              hipStream_t stream) {
    const float* adj  = (const float*)d_in[0];
    const float* data = (const float*)d_in[1];
    const float* pos  = (const float*)d_in[2];
    const float* hisW = (const float*)d_in[3];
    const float* curW = (const float*)d_in[4];
    const float* hisw = (const float*)d_in[5];
    const float* curw = (const float*)d_in[6];
    const float* fw   = (const float*)d_in[7];
    float* out = (float*)d_out;

    float* ws_agg = (float*)d_ws;                   // N*96 f32
    float* ws_fin = ws_agg + (size_t)NN * DIMD;     // N*96 f32

    agg_kernel<<<NB, 256, 0, stream>>>((const uint32*)adj, data, ws_agg);
    seq_kernel<<<(NN + 31) / 32, 256, 0, stream>>>(data, pos, hisW, curW,
                                                   hisw, curw, ws_agg, ws_fin);
    final_kernel<<<(NN + 31) / 32, 256, 0, stream>>>(ws_fin, fw, out);
}

// Round 11
// 51.141 us; speedup vs baseline: 1.1890x; 1.1890x over previous
//
#include <hip/hip_runtime.h>

#define NN 5000
#define TT 12
#define DAYD 8
#define FF 7
#define DIMD 96
#define SEGCAP 80
#define RPB 4      // rows per block -> MLP=20 preloaded chunks/thread

typedef unsigned int uint32;
typedef unsigned long long ull;
typedef uint32 uvec4 __attribute__((ext_vector_type(4)));

// ---------------------------------------------------------------------------
// Kernel 1: scan+gather, FOUR rows per block, 20 preloaded loads/thread.
//   AGG[n][t*8+d] = mean over nnz(adj[n]) of data[t][j][d]
// adj entries are exactly 1.0/0.0 -> deg == count; masks[1] == 0 because
// jnp.power is ELEMENTWISE and adj is binary (the L=2 mask vanishes).
// All 20 loads issue before any ballot; row r's ballot needs only its own 5
// -> compiler emits progressive vmcnt(15/10/5/0), rows 1-3 ride through
// row 0's compute. (Round-10 lesson: NO register rotation -> no vmcnt(0)
// drain; block-churn TLP across 1250 blocks does the rest.)
// ---------------------------------------------------------------------------
__global__ void __launch_bounds__(256)
agg_kernel(const uint32* __restrict__ adj,
           const float* __restrict__ data,
           float* __restrict__ agg_out) {
    __shared__ unsigned short s_cols[RPB][4][SEGCAP];
    __shared__ int s_wcnt[RPB][4];

    const int n0 = blockIdx.x * RPB;       // 1250 blocks x 4 rows = 5000
    const int tid = threadIdx.x;
    const int wave = tid >> 6, lane = tid & 63;
    const ull lmask = (1ull << lane) - 1ull;
    const int cbase = wave * 64 + lane;

    // Phase 1: preload all 4 rows (20 independent NT loads in flight)
    uvec4 v[RPB][5];
    #pragma unroll
    for (int r = 0; r < RPB; ++r) {
        const uvec4* row = (const uvec4*)(adj + (size_t)(n0 + r) * NN);
        #pragma unroll
        for (int i = 0; i < 5; ++i) {
            const int c = cbase + i * 256;  // 0..1279; valid < 1250
            v[r][i] = (c < 1250) ? __builtin_nontemporal_load(&row[c])
                                 : (uvec4)(0u, 0u, 0u, 0u);
        }
    }

    // Phase 2: ballot-compact each row into wave-private LDS segments
    #pragma unroll
    for (int r = 0; r < RPB; ++r) {
        int cnt = 0;
        #pragma unroll
        for (int i = 0; i < 5; ++i) {
            #pragma unroll
            for (int q = 0; q < 4; ++q) {
                const bool nz = v[r][i][q] != 0u;
                const ull m = __ballot(nz);
                if (nz) {
                    const int pos = cnt + (int)__popcll(m & lmask);
                    if (pos < SEGCAP)
                        s_cols[r][wave][pos] =
                            (unsigned short)((cbase + i * 256) * 4 + q);
                }
                cnt += (int)__popcll(m);
            }
        }
        if (lane == 0) s_wcnt[r][wave] = (cnt < SEGCAP) ? cnt : SEGCAP;
    }
    __syncthreads();

    // Phase 3: gather (96 threads; 4 independent row iterations, L2-resident)
    if (tid < DIMD) {
        const int t = tid >> 3, d = tid & 7;
        const float* db = data + (size_t)t * NN * DAYD + d;
        #pragma unroll
        for (int r = 0; r < RPB; ++r) {
            float acc = 0.f;
            int tot = 0;
            #pragma unroll
            for (int w2 = 0; w2 < 4; ++w2) {
                const int c = s_wcnt[r][w2];
                tot += c;
                const unsigned short* sc = s_cols[r][w2];
                int e = 0;
                for (; e + 4 <= c; e += 4) {
                    int j0 = sc[e], j1 = sc[e + 1], j2 = sc[e + 2], j3 = sc[e + 3];
                    acc += db[(size_t)j0 * 8] + db[(size_t)j1 * 8]
                         + db[(size_t)j2 * 8] + db[(size_t)j3 * 8];
                }
                for (; e < c; ++e) acc += db[(size_t)sc[e] * 8];
            }
            const float sc2 = (tot > 0) ? (1.f / (float)tot) : 0.f;
            agg_out[(size_t)(n0 + r) * DIMD + tid] = acc * sc2;
        }
    }
}

// ---------------------------------------------------------------------------
// Kernel 2: FUSED seq + final. 32 nodes/block (157 blocks), 256 threads.
// Phase A: sequential T-loop, 8 lanes/node (lane o<7 owns h[o]/run_his[o];
//   lane 7 owns the cur chain), h/c written to LDS s_fin (no global trip).
// Phase B: out = relu(s_fin @ fw^T) with fw LDS-staged [96][100].
// masks[1]==0: his_W cols 14..20 / cur_W col 2 skipped. Prefix matmuls are
// running accumulators (weight prefix never changes).
// ---------------------------------------------------------------------------
__global__ void __launch_bounds__(256)
seqfin_kernel(const float* __restrict__ data,
              const float* __restrict__ pos,
              const float* __restrict__ hisW,   // (T, F, 28)
              const float* __restrict__ curW,   // (T, 1, 4)
              const float* __restrict__ hisw,   // (F, 95)
              const float* __restrict__ curw,   // (1, 12)
              const float* __restrict__ agg,    // (N, 96)
              const float* __restrict__ fw,     // (96, 96)
              float* __restrict__ out) {        // (N, 96)
    __shared__ float s_W1[TT][8][24];   //  9,216 B
    __shared__ float s_W2[TT][8][8];    //  3,072 B
    __shared__ float s_CW[TT][4];       //    192 B
    __shared__ float s_fw[96 * 100];    // 38,400 B
    __shared__ float s_fin[32 * 97];    // 12,416 B   (total ~63.3 KB)
    float* s_out = s_fw;                // alias after all fw reads done

    const int tid = threadIdx.x;

    for (int i = tid; i < 96 * 96; i += 256) {
        int o = i / 96, k = i - o * 96;
        s_fw[o * 100 + k] = fw[i];
    }
    for (int i = tid; i < TT * 8 * 24; i += 256) {
        int t = i / (8 * 24), r = i - t * 8 * 24;
        int o = r / 24, k = r - o * 24;
        float v = 0.f;
        if (o < FF) {
            if (k < 14)      v = hisW[t * FF * 28 + o * 28 + k];
            else if (k < 21) v = hisW[t * FF * 28 + o * 28 + 21 + (k - 14)];
        }
        s_W1[t][o][k] = v;
    }
    for (int i = tid; i < TT * 8 * 8; i += 256) {
        int t = i / 64, r = i - t * 64;
        int o = r / 8, k = r - o * 8;
        s_W2[t][o][k] = (o < FF && k < FF) ? hisw[o * 95 + t * FF + k] : 0.f;
    }
    if (tid < TT * 4) {
        int t = tid >> 2, q = tid & 3;
        float v;
        if (q == 0)      v = curW[t * 4 + 0];
        else if (q == 1) v = curW[t * 4 + 1];
        else if (q == 2) v = curW[t * 4 + 3];
        else             v = curw[t];
        s_CW[t][q] = v;
    }
    __syncthreads();

    // ---- Phase A: sequential T-loop into s_fin ----
    const int g = tid >> 3;          // node slot in block (0..31)
    const int o = tid & 7;           // lane role
    const int nbase = blockIdx.x * 32;
    const int n = nbase + g;
    const int nc = (n < NN) ? n : (NN - 1);   // clamp for safe loads

    float hp = 0.f, run_his = 0.f;
    float run_cur = 0.f, cur_prev = 0.f;

    #pragma unroll
    for (int t = 0; t < TT; ++t) {
        const size_t dofs = ((size_t)t * NN + nc) * DAYD;
        float4 d0 = *(const float4*)(data + dofs);
        float4 d1 = *(const float4*)(data + dofs + 4);
        float4 a0 = *(const float4*)(agg + (size_t)nc * DIMD + t * 8);
        float4 a1 = *(const float4*)(agg + (size_t)nc * DIMD + t * 8 + 4);
        const float pv = pos[dofs + o];

        float hp0 = __shfl(hp, 0, 8), hp1 = __shfl(hp, 1, 8);
        float hp2 = __shfl(hp, 2, 8), hp3 = __shfl(hp, 3, 8);
        float hp4 = __shfl(hp, 4, 8), hp5 = __shfl(hp, 5, 8);
        float hp6 = __shfl(hp, 6, 8);

        const float4* wo = (const float4*)&s_W1[t][o][0];
        float4 w0 = wo[0], w1 = wo[1], w2 = wo[2];
        float4 w3 = wo[3], w4 = wo[4], w5 = wo[5];
        float s = d0.x * w0.x + d0.y * w0.y + d0.z * w0.z + d0.w * w0.w
                + d1.x * w1.x + d1.y * w1.y + d1.z * w1.z
                + a0.x * w1.w + a0.y * w2.x + a0.z * w2.y + a0.w * w2.z
                + a1.x * w2.w + a1.y * w3.x + a1.z * w3.y
                + hp0 * w3.z + hp1 * w3.w + hp2 * w4.x + hp3 * w4.y
                + hp4 * w4.z + hp5 * w4.w + hp6 * w5.x;
        const float h = fmaxf(s, 0.f) + pv;

        float h0 = __shfl(h, 0, 8), h1 = __shfl(h, 1, 8);
        float h2 = __shfl(h, 2, 8), h3 = __shfl(h, 3, 8);
        float h4 = __shfl(h, 4, 8), h5 = __shfl(h, 5, 8);
        float h6 = __shfl(h, 6, 8);

        const float4* uo = (const float4*)&s_W2[t][o][0];
        float4 u0 = uo[0], u1 = uo[1];
        run_his += h0 * u0.x + h1 * u0.y + h2 * u0.z + h3 * u0.w
                 + h4 * u1.x + h5 * u1.y + h6 * u1.z;
        hp = fmaxf(run_his, 0.f);

        if (o < FF) {
            s_fin[g * 97 + t * FF + o] = h;
        } else {
            float4 cw = *(const float4*)&s_CW[t][0];
            float c = d1.w * cw.x + a1.w * cw.y + cur_prev * cw.z;
            c = fmaxf(c, 0.f) + pv;
            s_fin[g * 97 + 84 + t] = c;
            run_cur += c * cw.w;
            cur_prev = fmaxf(run_cur, 0.f);
        }
    }
    __syncthreads();

    // ---- Phase B: out = relu(s_fin @ fw^T) ----
    const int wave = tid >> 6, lane = tid & 63;
    const int node = lane & 31, dup = lane >> 5;
    const int obase = wave * 24 + dup * 12;

    float acc[12];
    #pragma unroll
    for (int oo = 0; oo < 12; ++oo) acc[oo] = 0.f;

    #pragma unroll 2
    for (int k0 = 0; k0 < DIMD; k0 += 4) {
        float f0 = s_fin[node * 97 + k0 + 0];
        float f1 = s_fin[node * 97 + k0 + 1];
        float f2 = s_fin[node * 97 + k0 + 2];
        float f3 = s_fin[node * 97 + k0 + 3];
        #pragma unroll
        for (int oo = 0; oo < 12; ++oo) {
            float4 w = *(const float4*)&s_fw[(obase + oo) * 100 + k0];
            acc[oo] += f0 * w.x + f1 * w.y + f2 * w.z + f3 * w.w;
        }
    }
    __syncthreads();   // all fw reads done; s_out may alias s_fw

    #pragma unroll
    for (int oo = 0; oo < 12; ++oo)
        s_out[node * 97 + obase + oo] = fmaxf(acc[oo], 0.f);
    __syncthreads();

    for (int i = tid; i < 32 * DIMD; i += 256) {
        int r = i / DIMD, c = i - r * DIMD;
        int nn = nbase + r;
        if (nn < NN) out[(size_t)nn * DIMD + c] = s_out[r * 97 + c];
    }
}

extern "C" void kernel_launch(void* const* d_in, const int* in_sizes, int n_in,
                              void* d_out, int out_size, void* d_ws, size_t ws_size,
                              hipStream_t stream) {
    const float* adj  = (const float*)d_in[0];
    const float* data = (const float*)d_in[1];
    const float* pos  = (const float*)d_in[2];
    const float* hisW = (const float*)d_in[3];
    const float* curW = (const float*)d_in[4];
    const float* hisw = (const float*)d_in[5];
    const float* curw = (const float*)d_in[6];
    const float* fw   = (const float*)d_in[7];
    float* out = (float*)d_out;

    float* ws_agg = (float*)d_ws;   // N*96 f32

    agg_kernel<<<NN / RPB, 256, 0, stream>>>((const uint32*)adj, data, ws_agg);
    seqfin_kernel<<<(NN + 31) / 32, 256, 0, stream>>>(data, pos, hisW, curW,
                                                      hisw, curw, ws_agg, fw, out);
}

// Round 12
// 47.412 us; speedup vs baseline: 1.2825x; 1.0786x over previous
//
#include <hip/hip_runtime.h>

#define NN 5000
#define TT 12
#define DAYD 8
#define FF 7
#define DIMD 96
#define SEGCAP 64

typedef unsigned int uint32;
typedef unsigned long long ull;
typedef uint32 uvec4 __attribute__((ext_vector_type(4)));

// ---------------------------------------------------------------------------
// Kernel 1: scan+gather, 2 rows/block, MLP=10, ONE ballot per 16B chunk.
//   AGG[n][t*8+d] = mean over nnz(adj[n]) of data[t][j][d]
// adj entries are exactly 1.0/0.0 -> deg == count; masks[1] == 0 because
// jnp.power is ELEMENTWISE and adj is binary (the L=2 mask vanishes).
// Round-12 theory: the scan limiter is the per-16B ballot/popc dependency
// tail (4 chained ballots per chunk). Fix: one ballot on (x|y|z|w)!=0;
// only hit lanes (~2%) extract indices, reserving slots via a per-wave LDS
// cursor (ds_add_rtn is lane-ordered -> deterministic layout).
// ---------------------------------------------------------------------------
__global__ void __launch_bounds__(256)
agg_kernel(const uint32* __restrict__ adj,
           const float* __restrict__ data,
           float* __restrict__ agg_out) {
    __shared__ unsigned short s_cols[2][4][SEGCAP];
    __shared__ int s_cnt[2][4];

    const int n0 = blockIdx.x * 2;
    const int tid = threadIdx.x;
    const int wave = tid >> 6, lane = tid & 63;
    const int cbase = wave * 64 + lane;

    if (lane == 0) { s_cnt[0][wave] = 0; s_cnt[1][wave] = 0; }
    // same-wave DS ordering: later ds_add_rtn from this wave sees the reset

    const uvec4* r0 = (const uvec4*)(adj + (size_t)n0 * NN);        // 1250
    const uvec4* r1 = (const uvec4*)(adj + (size_t)(n0 + 1) * NN);

    // Phase 1: preload both rows (10 independent NT loads in flight)
    uvec4 v0[5], v1[5];
    #pragma unroll
    for (int i = 0; i < 5; ++i) {
        const int c = cbase + i * 256;   // 0..1279; valid < 1250
        if (c < 1250) {
            v0[i] = __builtin_nontemporal_load(&r0[c]);
            v1[i] = __builtin_nontemporal_load(&r1[c]);
        } else {
            v0[i] = (uvec4)(0u, 0u, 0u, 0u);
            v1[i] = (uvec4)(0u, 0u, 0u, 0u);
        }
    }

    // Phase 2: one-ballot-per-chunk extraction, per row
#define SCAN_ROW(R, V)                                                       \
    {                                                                        \
        _Pragma("unroll")                                                    \
        for (int i = 0; i < 5; ++i) {                                        \
            const uvec4 v = V[i];                                            \
            const uint32 any = v[0] | v[1] | v[2] | v[3];                    \
            const ull m = __ballot(any != 0u);                               \
            if (m != 0ull) {                                                 \
                if (any != 0u) {                                             \
                    const int c0 = (cbase + i * 256) * 4;                    \
                    const int cl = (v[0] != 0u) + (v[1] != 0u)               \
                                 + (v[2] != 0u) + (v[3] != 0u);              \
                    int pos = atomicAdd(&s_cnt[R][wave], cl);                \
                    if (v[0] != 0u) { if (pos < SEGCAP)                      \
                        s_cols[R][wave][pos] = (unsigned short)(c0 + 0);     \
                        ++pos; }                                             \
                    if (v[1] != 0u) { if (pos < SEGCAP)                      \
                        s_cols[R][wave][pos] = (unsigned short)(c0 + 1);     \
                        ++pos; }                                             \
                    if (v[2] != 0u) { if (pos < SEGCAP)                      \
                        s_cols[R][wave][pos] = (unsigned short)(c0 + 2);     \
                        ++pos; }                                             \
                    if (v[3] != 0u) { if (pos < SEGCAP)                      \
                        s_cols[R][wave][pos] = (unsigned short)(c0 + 3);     \
                        ++pos; }                                             \
                }                                                            \
            }                                                                \
        }                                                                    \
    }

    SCAN_ROW(0, v0)
    SCAN_ROW(1, v1)
#undef SCAN_ROW
    __syncthreads();

    // Phase 3: gather (192 threads = 96 outputs x 2 rows; data L2-resident)
    if (tid < 192) {
        const int row = (tid >= 96) ? 1 : 0;
        const int k = tid - row * 96;
        const int t = k >> 3, d = k & 7;
        const float* db = data + (size_t)t * NN * DAYD + d;
        float acc = 0.f;
        int tot = 0;
        #pragma unroll
        for (int w2 = 0; w2 < 4; ++w2) {
            int c = s_cnt[row][w2];
            c = (c < SEGCAP) ? c : SEGCAP;
            tot += c;
            const unsigned short* sc = s_cols[row][w2];
            int e = 0;
            for (; e + 4 <= c; e += 4) {
                int j0 = sc[e], j1 = sc[e + 1], j2 = sc[e + 2], j3 = sc[e + 3];
                acc += db[(size_t)j0 * 8] + db[(size_t)j1 * 8]
                     + db[(size_t)j2 * 8] + db[(size_t)j3 * 8];
            }
            for (; e < c; ++e) acc += db[(size_t)sc[e] * 8];
        }
        const float sc2 = (tot > 0) ? (1.f / (float)tot) : 0.f;
        agg_out[(size_t)(n0 + row) * DIMD + k] = acc * sc2;
    }
}

// ---------------------------------------------------------------------------
// Kernel 2: FUSED seq + final (unchanged from round 11).
// Phase A: sequential T-loop, 8 lanes/node, h/c -> LDS s_fin.
// Phase B: out = relu(s_fin @ fw^T), fw LDS-staged [96][100].
// masks[1]==0: his_W cols 14..20 / cur_W col 2 skipped. Prefix matmuls are
// running accumulators (weight prefix never changes).
// ---------------------------------------------------------------------------
__global__ void __launch_bounds__(256)
seqfin_kernel(const float* __restrict__ data,
              const float* __restrict__ pos,
              const float* __restrict__ hisW,   // (T, F, 28)
              const float* __restrict__ curW,   // (T, 1, 4)
              const float* __restrict__ hisw,   // (F, 95)
              const float* __restrict__ curw,   // (1, 12)
              const float* __restrict__ agg,    // (N, 96)
              const float* __restrict__ fw,     // (96, 96)
              float* __restrict__ out) {        // (N, 96)
    __shared__ float s_W1[TT][8][24];
    __shared__ float s_W2[TT][8][8];
    __shared__ float s_CW[TT][4];
    __shared__ float s_fw[96 * 100];
    __shared__ float s_fin[32 * 97];
    float* s_out = s_fw;

    const int tid = threadIdx.x;

    for (int i = tid; i < 96 * 96; i += 256) {
        int o = i / 96, k = i - o * 96;
        s_fw[o * 100 + k] = fw[i];
    }
    for (int i = tid; i < TT * 8 * 24; i += 256) {
        int t = i / (8 * 24), r = i - t * 8 * 24;
        int o = r / 24, k = r - o * 24;
        float v = 0.f;
        if (o < FF) {
            if (k < 14)      v = hisW[t * FF * 28 + o * 28 + k];
            else if (k < 21) v = hisW[t * FF * 28 + o * 28 + 21 + (k - 14)];
        }
        s_W1[t][o][k] = v;
    }
    for (int i = tid; i < TT * 8 * 8; i += 256) {
        int t = i / 64, r = i - t * 64;
        int o = r / 8, k = r - o * 8;
        s_W2[t][o][k] = (o < FF && k < FF) ? hisw[o * 95 + t * FF + k] : 0.f;
    }
    if (tid < TT * 4) {
        int t = tid >> 2, q = tid & 3;
        float v;
        if (q == 0)      v = curW[t * 4 + 0];
        else if (q == 1) v = curW[t * 4 + 1];
        else if (q == 2) v = curW[t * 4 + 3];
        else             v = curw[t];
        s_CW[t][q] = v;
    }
    __syncthreads();

    const int g = tid >> 3;
    const int o = tid & 7;
    const int nbase = blockIdx.x * 32;
    const int n = nbase + g;
    const int nc = (n < NN) ? n : (NN - 1);

    float hp = 0.f, run_his = 0.f;
    float run_cur = 0.f, cur_prev = 0.f;

    #pragma unroll
    for (int t = 0; t < TT; ++t) {
        const size_t dofs = ((size_t)t * NN + nc) * DAYD;
        float4 d0 = *(const float4*)(data + dofs);
        float4 d1 = *(const float4*)(data + dofs + 4);
        float4 a0 = *(const float4*)(agg + (size_t)nc * DIMD + t * 8);
        float4 a1 = *(const float4*)(agg + (size_t)nc * DIMD + t * 8 + 4);
        const float pv = pos[dofs + o];

        float hp0 = __shfl(hp, 0, 8), hp1 = __shfl(hp, 1, 8);
        float hp2 = __shfl(hp, 2, 8), hp3 = __shfl(hp, 3, 8);
        float hp4 = __shfl(hp, 4, 8), hp5 = __shfl(hp, 5, 8);
        float hp6 = __shfl(hp, 6, 8);

        const float4* wo = (const float4*)&s_W1[t][o][0];
        float4 w0 = wo[0], w1 = wo[1], w2 = wo[2];
        float4 w3 = wo[3], w4 = wo[4], w5 = wo[5];
        float s = d0.x * w0.x + d0.y * w0.y + d0.z * w0.z + d0.w * w0.w
                + d1.x * w1.x + d1.y * w1.y + d1.z * w1.z
                + a0.x * w1.w + a0.y * w2.x + a0.z * w2.y + a0.w * w2.z
                + a1.x * w2.w + a1.y * w3.x + a1.z * w3.y
                + hp0 * w3.z + hp1 * w3.w + hp2 * w4.x + hp3 * w4.y
                + hp4 * w4.z + hp5 * w4.w + hp6 * w5.x;
        const float h = fmaxf(s, 0.f) + pv;

        float h0 = __shfl(h, 0, 8), h1 = __shfl(h, 1, 8);
        float h2 = __shfl(h, 2, 8), h3 = __shfl(h, 3, 8);
        float h4 = __shfl(h, 4, 8), h5 = __shfl(h, 5, 8);
        float h6 = __shfl(h, 6, 8);

        const float4* uo = (const float4*)&s_W2[t][o][0];
        float4 u0 = uo[0], u1 = uo[1];
        run_his += h0 * u0.x + h1 * u0.y + h2 * u0.z + h3 * u0.w
                 + h4 * u1.x + h5 * u1.y + h6 * u1.z;
        hp = fmaxf(run_his, 0.f);

        if (o < FF) {
            s_fin[g * 97 + t * FF + o] = h;
        } else {
            float4 cw = *(const float4*)&s_CW[t][0];
            float c = d1.w * cw.x + a1.w * cw.y + cur_prev * cw.z;
            c = fmaxf(c, 0.f) + pv;
            s_fin[g * 97 + 84 + t] = c;
            run_cur += c * cw.w;
            cur_prev = fmaxf(run_cur, 0.f);
        }
    }
    __syncthreads();

    const int wave = tid >> 6, lane = tid & 63;
    const int node = lane & 31, dup = lane >> 5;
    const int obase = wave * 24 + dup * 12;

    float acc[12];
    #pragma unroll
    for (int oo = 0; oo < 12; ++oo) acc[oo] = 0.f;

    #pragma unroll 2
    for (int k0 = 0; k0 < DIMD; k0 += 4) {
        float f0 = s_fin[node * 97 + k0 + 0];
        float f1 = s_fin[node * 97 + k0 + 1];
        float f2 = s_fin[node * 97 + k0 + 2];
        float f3 = s_fin[node * 97 + k0 + 3];
        #pragma unroll
        for (int oo = 0; oo < 12; ++oo) {
            float4 w = *(const float4*)&s_fw[(obase + oo) * 100 + k0];
            acc[oo] += f0 * w.x + f1 * w.y + f2 * w.z + f3 * w.w;
        }
    }
    __syncthreads();

    #pragma unroll
    for (int oo = 0; oo < 12; ++oo)
        s_out[node * 97 + obase + oo] = fmaxf(acc[oo], 0.f);
    __syncthreads();

    for (int i = tid; i < 32 * DIMD; i += 256) {
        int r = i / DIMD, c = i - r * DIMD;
        int nn = nbase + r;
        if (nn < NN) out[(size_t)nn * DIMD + c] = s_out[r * 97 + c];
    }
}

extern "C" void kernel_launch(void* const* d_in, const int* in_sizes, int n_in,
                              void* d_out, int out_size, void* d_ws, size_t ws_size,
                              hipStream_t stream) {
    const float* adj  = (const float*)d_in[0];
    const float* data = (const float*)d_in[1];
    const float* pos  = (const float*)d_in[2];
    const float* hisW = (const float*)d_in[3];
    const float* curW = (const float*)d_in[4];
    const float* hisw = (const float*)d_in[5];
    const float* curw = (const float*)d_in[6];
    const float* fw   = (const float*)d_in[7];
    float* out = (float*)d_out;

    float* ws_agg = (float*)d_ws;   // N*96 f32

    agg_kernel<<<NN / 2, 256, 0, stream>>>((const uint32*)adj, data, ws_agg);
    seqfin_kernel<<<(NN + 31) / 32, 256, 0, stream>>>(data, pos, hisW, curW,
                                                      hisw, curw, ws_agg, fw, out);
}